// Round 5
// baseline (2515.229 us; speedup 1.0000x reference)
//
#include <hip/hip_runtime.h>

typedef unsigned short u16;

#define DEVFN static __device__ __forceinline__

constexpr int Sq = 2048, Dm = 1024, NH = 16, HDim = 64, NE = 8, FHid = 4096;

typedef __attribute__((ext_vector_type(8))) short bf16x8;
typedef __attribute__((ext_vector_type(4))) float f32x4;

DEVFN float b2f(u16 u) { return __uint_as_float(((unsigned)u) << 16); }
// round-to-nearest-even f32 -> bf16
DEVFN u16 f2b(float f) {
  unsigned u = __float_as_uint(f);
  return (u16)((u + 0x7fffu + ((u >> 16) & 1u)) >> 16);
}
DEVFN float gelu_f(float x) {
  float y = 0.7978845608028654f * (x + 0.044715f * x * x * x);
  float t = 1.0f - 2.0f / (__expf(2.0f * y) + 1.0f);
  return 0.5f * x * (1.0f + t);
}

DEVFN void gload16(const u16* g, u16* l) {
  __builtin_amdgcn_global_load_lds((const __attribute__((address_space(1))) void*)g,
                                   (__attribute__((address_space(3))) void*)l, 16, 0, 0);
}

// ---------------- input dtype detector: flag=1 if inputs are f32 ----------------
__global__ __launch_bounds__(256) void detect_k(const u16* __restrict__ x, int* __restrict__ flag) {
  int t = threadIdx.x;
  float mx = 0.f;
  for (int i = t; i < 4096; i += 256) mx = fmaxf(mx, fabsf(b2f(x[i])));
#pragma unroll
  for (int m = 32; m; m >>= 1) mx = fmaxf(mx, __shfl_xor(mx, m, 64));
  __shared__ float red[4];
  if ((t & 63) == 0) red[t >> 6] = mx;
  __syncthreads();
  if (t == 0) {
    float m2 = fmaxf(fmaxf(red[0], red[1]), fmaxf(red[2], red[3]));
    flag[0] = (m2 > 1e6f) ? 1 : 0;
  }
}

// ---- rmsnorm: ONE WAVE per row, shuffle reduction.
// INM: 0=ws f32, 1=input(flag), 2=sum of two f32 ws buffers (inp+inp2).
// RESM: 0=none,1=ws f32,2=input(flag). OUT: always f32.
template <int INM, int RESM>
__global__ __launch_bounds__(64) void rmsnorm2_k(const void* __restrict__ inp, const void* __restrict__ g,
                                                 const void* __restrict__ resp, float* __restrict__ out1,
                                                 const int* __restrict__ dflag,
                                                 const void* __restrict__ inp2) {
  int isf = dflag[0];
  int row = blockIdx.x, t = threadIdx.x;  // 64 threads
  long rb = (long)row * Dm;
  float v[16];
#pragma unroll
  for (int j = 0; j < 4; j++) {
    long o = rb + t * 4 + j * 256;
    if constexpr (INM == 2) {
      float4 f = *((const float4*)((const float*)inp + o));
      float4 f2 = *((const float4*)((const float*)inp2 + o));
      v[4 * j] = f.x + f2.x; v[4 * j + 1] = f.y + f2.y;
      v[4 * j + 2] = f.z + f2.z; v[4 * j + 3] = f.w + f2.w;
    } else if (INM == 0 || isf) {
      float4 f = *((const float4*)((const float*)inp + o));
      v[4 * j] = f.x; v[4 * j + 1] = f.y; v[4 * j + 2] = f.z; v[4 * j + 3] = f.w;
    } else {
      ushort4 u = *((const ushort4*)((const u16*)inp + o));
      v[4 * j] = b2f(u.x); v[4 * j + 1] = b2f(u.y); v[4 * j + 2] = b2f(u.z); v[4 * j + 3] = b2f(u.w);
    }
  }
  float ss = 0.f;
#pragma unroll
  for (int j = 0; j < 16; j++) ss += v[j] * v[j];
#pragma unroll
  for (int m = 32; m; m >>= 1) ss += __shfl_xor(ss, m, 64);
  float sc = rsqrtf(ss * (1.0f / Dm) + 1e-5f);
#pragma unroll
  for (int j = 0; j < 4; j++) {
    long o = rb + t * 4 + j * 256;
    int go = t * 4 + j * 256;
    float gf[4];
    if (isf) {
      float4 gv = *((const float4*)((const float*)g + go));
      gf[0] = gv.x; gf[1] = gv.y; gf[2] = gv.z; gf[3] = gv.w;
    } else {
      ushort4 gu = *((const ushort4*)((const u16*)g + go));
      gf[0] = b2f(gu.x); gf[1] = b2f(gu.y); gf[2] = b2f(gu.z); gf[3] = b2f(gu.w);
    }
    float o4[4];
#pragma unroll
    for (int q = 0; q < 4; q++) o4[q] = v[4 * j + q] * sc * gf[q];
    if constexpr (RESM == 1) {
      float4 rf = *((const float4*)((const float*)resp + o));
      o4[0] += rf.x; o4[1] += rf.y; o4[2] += rf.z; o4[3] += rf.w;
    } else if constexpr (RESM == 2) {
      if (isf) {
        float4 rf = *((const float4*)((const float*)resp + o));
        o4[0] += rf.x; o4[1] += rf.y; o4[2] += rf.z; o4[3] += rf.w;
      } else {
        ushort4 ru = *((const ushort4*)((const u16*)resp + o));
        o4[0] += b2f(ru.x); o4[1] += b2f(ru.y); o4[2] += b2f(ru.z); o4[3] += b2f(ru.w);
      }
    }
    float4 of;
    of.x = o4[0]; of.y = o4[1]; of.z = o4[2]; of.w = o4[3];
    *((float4*)(out1 + o)) = of;
  }
}

// ---------------- naive tiled f32 GEMM 64x64 (Wk/Wv; arithmetic VERBATIM baseline) ---
template <int OP>
__global__ __launch_bounds__(256) void gemm_nn_k(
    const float* __restrict__ A, const void* __restrict__ Braw, long boff,
    float* __restrict__ C, int M, int N, int K,
    const float* __restrict__ wfull, int eidx, const int* __restrict__ dflag) {
  int isf = dflag[0];
  const float* Bf = (const float*)Braw;
  const u16* Bh = (const u16*)Braw;
  int t = threadIdx.x;
  int m0 = blockIdx.y * 64, n0 = blockIdx.x * 64;

  __shared__ float As[64][20];
  __shared__ float Bs[16][68];

  int ty = t >> 4, tx = t & 15;
  float acc[4][4];
#pragma unroll
  for (int i = 0; i < 4; i++)
#pragma unroll
    for (int j = 0; j < 4; j++) acc[i][j] = 0.f;

  for (int k0 = 0; k0 < K; k0 += 16) {
    __syncthreads();
#pragma unroll
    for (int i = 0; i < 4; i++) {
      int idx = t + i * 256;
      int ar = idx >> 4, ac = idx & 15;
      As[ar][ac] = A[(long)(m0 + ar) * K + k0 + ac];
      int br = idx >> 6, bc = idx & 63;
      long bi = boff + (long)(k0 + br) * N + n0 + bc;
      Bs[br][bc] = isf ? Bf[bi] : b2f(Bh[bi]);
    }
    __syncthreads();
#pragma unroll
    for (int kk = 0; kk < 16; kk++) {
      float a[4], b[4];
#pragma unroll
      for (int i = 0; i < 4; i++) a[i] = As[ty * 4 + i][kk];
#pragma unroll
      for (int j = 0; j < 4; j++) b[j] = Bs[kk][tx * 4 + j];
#pragma unroll
      for (int i = 0; i < 4; i++)
#pragma unroll
        for (int j = 0; j < 4; j++) acc[i][j] += a[i] * b[j];
    }
  }
#pragma unroll
  for (int i = 0; i < 4; i++) {
    int row = m0 + ty * 4 + i;
#pragma unroll
    for (int j = 0; j < 4; j++) {
      int col = n0 + tx * 4 + j;
      long cidx = (long)row * N + col;
      float val = acc[i][j];
      if constexpr (OP == 0) C[cidx] = val;
      else if constexpr (OP == 1) C[cidx] = gelu_f(val);
      else C[cidx] += wfull[(long)row * 8 + eidx] * val;
    }
  }
}

// ---------------- f32 GEMM 128x64 tile, 8x4 acc/thread (Wq/Wo).
// Per-output-element FMA chain identical to baseline (same k0/kk order) => bit-exact. ---
__global__ __launch_bounds__(256) void gemm_big_k(
    const float* __restrict__ A, const void* __restrict__ Braw,
    float* __restrict__ C, int M, int N, int K, const int* __restrict__ dflag) {
  int isf = dflag[0];
  const float* Bf = (const float*)Braw;
  const u16* Bh = (const u16*)Braw;
  int t = threadIdx.x;
  int m0 = blockIdx.y * 128, n0 = blockIdx.x * 64;

  __shared__ float As[128][21];  // pad 21: (r*21+kk)%32 spreads 4-way ty groups
  __shared__ float Bs[16][68];

  int ty = t >> 4, tx = t & 15;  // ty 0..15 (8 rows each), tx 0..15 (4 cols each)
  float acc[8][4];
#pragma unroll
  for (int i = 0; i < 8; i++)
#pragma unroll
    for (int j = 0; j < 4; j++) acc[i][j] = 0.f;

  for (int k0 = 0; k0 < K; k0 += 16) {
    __syncthreads();
#pragma unroll
    for (int i = 0; i < 8; i++) {
      int idx = t + i * 256;
      int ar = idx >> 4, ac = idx & 15;
      As[ar][ac] = A[(long)(m0 + ar) * K + k0 + ac];
    }
#pragma unroll
    for (int i = 0; i < 4; i++) {
      int idx = t + i * 256;
      int br = idx >> 6, bc = idx & 63;
      long bi = (long)(k0 + br) * N + n0 + bc;
      Bs[br][bc] = isf ? Bf[bi] : b2f(Bh[bi]);
    }
    __syncthreads();
#pragma unroll
    for (int kk = 0; kk < 16; kk++) {
      float a[8], b[4];
#pragma unroll
      for (int i = 0; i < 8; i++) a[i] = As[ty * 8 + i][kk];
#pragma unroll
      for (int j = 0; j < 4; j++) b[j] = Bs[kk][tx * 4 + j];
#pragma unroll
      for (int i = 0; i < 8; i++)
#pragma unroll
        for (int j = 0; j < 4; j++) acc[i][j] += a[i] * b[j];
    }
  }
#pragma unroll
  for (int i = 0; i < 8; i++) {
    int row = m0 + ty * 8 + i;
#pragma unroll
    for (int j = 0; j < 4; j++) {
      int col = n0 + tx * 4 + j;
      C[(long)row * N + col] = acc[i][j];
    }
  }
}

// ---------------- plain-f32 attention (R4-verbatim: bit-exact, aligned LDS) ----
__global__ __launch_bounds__(256) void attn_f32_k(
    const float* __restrict__ Qf, const float* __restrict__ Kf, const float* __restrict__ Vf,
    float* __restrict__ Of) {
  int qb = blockIdx.x, h = blockIdx.y;
  int t = threadIdx.x;
  int qr = t >> 2;
  int sub = t & 3;
  __shared__ float Ks[64][68];
  __shared__ float Vs[64][68];
  int qrow = qb * 64 + qr;
  const float* qp = Qf + (long)qrow * Dm + h * HDim + sub * 16;
  float qfr[16];
#pragma unroll
  for (int j = 0; j < 16; j += 4) {
    float4 v = *(const float4*)(qp + j);
    qfr[j] = v.x; qfr[j + 1] = v.y; qfr[j + 2] = v.z; qfr[j + 3] = v.w;
  }
  float o[16];
#pragma unroll
  for (int j = 0; j < 16; j++) o[j] = 0.f;
  float m_i = -3e38f, l_i = 0.f;

  for (int kb = 0; kb < Sq / 64; kb++) {
    __syncthreads();
#pragma unroll
    for (int i = 0; i < 2; i++) {
      int idx = t + i * 256;
      int r = idx >> 3, c8 = (idx & 7) * 8;
      const float* kp = Kf + (long)(kb * 64 + r) * HDim + c8;
      float4 a = *(const float4*)(kp);
      float4 b = *(const float4*)(kp + 4);
      *(float4*)&Ks[r][c8] = a;
      *(float4*)&Ks[r][c8 + 4] = b;
      const float* vp = Vf + (long)(kb * 64 + r) * HDim + c8;
      float4 c = *(const float4*)(vp);
      float4 d = *(const float4*)(vp + 4);
      *(float4*)&Vs[r][c8] = c;
      *(float4*)&Vs[r][c8 + 4] = d;
    }
    __syncthreads();
    float s[64];
#pragma unroll
    for (int j = 0; j < 64; j++) {
      float acc = 0.f;
#pragma unroll
      for (int d = 0; d < 16; d++) acc += qfr[d] * Ks[j][sub * 16 + d];
      s[j] = acc;
    }
#pragma unroll
    for (int j = 0; j < 64; j++) {
      float v = s[j];
      v += __shfl_xor(v, 1, 64);
      v += __shfl_xor(v, 2, 64);
      s[j] = v * 0.125f;
    }
    float mx = s[0];
#pragma unroll
    for (int j = 1; j < 64; j++) mx = fmaxf(mx, s[j]);
    float mn = fmaxf(m_i, mx);
    float alpha = __expf(m_i - mn);
    m_i = mn;
    float ps = 0.f;
#pragma unroll
    for (int j = 0; j < 64; j++) {
      s[j] = __expf(s[j] - mn);
      ps += s[j];
    }
    l_i = l_i * alpha + ps;
#pragma unroll
    for (int d = 0; d < 16; d++) o[d] *= alpha;
#pragma unroll
    for (int j = 0; j < 64; j++)
#pragma unroll
      for (int d = 0; d < 16; d++) o[d] += s[j] * Vs[j][sub * 16 + d];
  }
  float inv = 1.0f / l_i;
#pragma unroll
  for (int d = 0; d < 16; d++)
    Of[(long)qrow * Dm + h * HDim + sub * 16 + d] = o[d] * inv;
}

// ---- router: ONE LANE PER (token, expert). Per-(tok,e) accumulation chain is the
// baseline's exact sequential i-order (float4 loads don't alter fma order); top-2
// scan replicated per-lane on shfl-gathered logits => selection bit-identical.
__global__ __launch_bounds__(256) void router2_k(const float* __restrict__ h2, const void* __restrict__ Wr,
                                                 float* __restrict__ probs_out, float* __restrict__ wfull,
                                                 const int* __restrict__ dflag,
                                                 int* __restrict__ ecnt, int* __restrict__ elist) {
  int isf = dflag[0];
  int gid = blockIdx.x * 256 + threadIdx.x;
  int tok = gid >> 3, e = gid & 7;
  if (tok >= Sq) return;
  const float* hrow = h2 + (long)tok * Dm;
  float acc = 0.f;
  if (isf) {
    const float* wr = (const float*)Wr;
    for (int i = 0; i < Dm; i += 4) {
      float4 h4 = *(const float4*)(hrow + i);
      acc += h4.x * wr[(long)i * 8 + e];
      acc += h4.y * wr[(long)(i + 1) * 8 + e];
      acc += h4.z * wr[(long)(i + 2) * 8 + e];
      acc += h4.w * wr[(long)(i + 3) * 8 + e];
    }
  } else {
    const u16* wr = (const u16*)Wr;
    for (int i = 0; i < Dm; i += 4) {
      float4 h4 = *(const float4*)(hrow + i);
      acc += h4.x * b2f(wr[(long)i * 8 + e]);
      acc += h4.y * b2f(wr[(long)(i + 1) * 8 + e]);
      acc += h4.z * b2f(wr[(long)(i + 2) * 8 + e]);
      acc += h4.w * b2f(wr[(long)(i + 3) * 8 + e]);
    }
  }
  // gather the 8 expert logits of this token into every lane of the group
  int lane = threadIdx.x & 63;
  int gbase = lane & ~7;
  float vals[8];
#pragma unroll
  for (int e2 = 0; e2 < 8; e2++) vals[e2] = __shfl(acc, gbase + e2, 64);
  // baseline-identical top-2 scan
  int i1 = 0;
#pragma unroll
  for (int e2 = 1; e2 < 8; e2++)
    if (vals[e2] > vals[i1]) i1 = e2;
  int i2 = (i1 == 0) ? 1 : 0;
#pragma unroll
  for (int e2 = 0; e2 < 8; e2++)
    if (e2 != i1 && vals[e2] > vals[i2]) i2 = e2;
  float mx = vals[i1];
  float pr[8], s = 0.f;
#pragma unroll
  for (int e2 = 0; e2 < 8; e2++) { pr[e2] = expf(vals[e2] - mx); s += pr[e2]; }
  float inv = 1.0f / s;
  float pe = pr[e] * inv;
  probs_out[(long)tok * 8 + e] = pe;
  wfull[(long)tok * 8 + e] = (e == i1 || e == i2) ? pe : 0.f;
  if (e == 0) {
    int p1 = atomicAdd(&ecnt[i1], 1);
    elist[i1 * Sq + p1] = tok;
    int p2 = atomicAdd(&ecnt[i2], 1);
    elist[i2 * Sq + p2] = tok;
  }
}

// ---- split f32 -> (hi, lo) bf16 pair (2^-16): MoE h2 (post-router) ----
__global__ __launch_bounds__(256) void split_pair_k(const float* __restrict__ in, u16* __restrict__ hi,
                                                    u16* __restrict__ lo, int n4) {
  int i = blockIdx.x * 256 + threadIdx.x;
  if (i >= n4) return;
  float4 v = ((const float4*)in)[i];
  ushort4 h, l;
  h.x = f2b(v.x); l.x = f2b(v.x - b2f(h.x));
  h.y = f2b(v.y); l.y = f2b(v.y - b2f(h.y));
  h.z = f2b(v.z); l.z = f2b(v.z - b2f(h.z));
  h.w = f2b(v.w); l.w = f2b(v.w - b2f(h.w));
  ((ushort4*)hi)[i] = h;
  ((ushort4*)lo)[i] = l;
}

// ---- fused per-expert transposes: z=0: W1[e] [Dm][FHid] -> bt1 [FHid][Dm];
//                                   z=1: W2[e] [FHid][Dm] -> bt2 [Dm][FHid].
__global__ __launch_bounds__(256) void transpose2_k(const void* __restrict__ W1p, const void* __restrict__ W2p,
                                                    long boff, u16* __restrict__ bt1, u16* __restrict__ bt2,
                                                    const int* __restrict__ dflag) {
  int isf = dflag[0];
  int z = blockIdx.z;
  const void* B = z ? W2p : W1p;
  u16* BT = z ? bt2 : bt1;
  int K = z ? FHid : Dm;  // source rows
  int N = z ? Dm : FHid;  // source cols
  int n0 = blockIdx.x * 32, k0 = blockIdx.y * 32;
  if (n0 >= N || k0 >= K) return;
  __shared__ u16 tile[32][33];
  int tx = threadIdx.x & 31, ty = threadIdx.x >> 5;
#pragma unroll
  for (int j = 0; j < 32; j += 8) {
    long idx = boff + (long)(k0 + ty + j) * N + n0 + tx;
    u16 uv = isf ? f2b(((const float*)B)[idx]) : ((const u16*)B)[idx];
    tile[ty + j][tx] = uv;
  }
  __syncthreads();
#pragma unroll
  for (int j = 0; j < 32; j += 8)
    BT[(long)(n0 + ty + j) * K + k0 + tx] = tile[tx][ty + j];
}

// ---- SPARSE MoE W1 (R4-verbatim): hid'[r] = split(gelu(h2[tok(r)] @ W1T^T) * w). ----
__global__ __launch_bounds__(256) void moe_w1_k(
    const u16* __restrict__ Ah, const u16* __restrict__ Al, const u16* __restrict__ BT,
    u16* __restrict__ Ch, u16* __restrict__ Cl, const float* __restrict__ wfull,
    const int* __restrict__ elist, const int* __restrict__ ecnt, int eidx) {
  constexpr int N = FHid, K = Dm;
  int cnt = ecnt[eidx];
  int m0 = blockIdx.y * 128, n0 = blockIdx.x * 128;
  if (m0 >= cnt) return;
  __shared__ __align__(16) u16 sAh[128 * 32];
  __shared__ __align__(16) u16 sAl[128 * 32];
  __shared__ __align__(16) u16 sBT[128 * 32];
  __shared__ int sTok[128];
  int t = threadIdx.x;
  if (t < 128) {
    int r = m0 + t;
    sTok[t] = (r < cnt) ? elist[eidx * Sq + r] : elist[eidx * Sq];
  }
  int l = t & 63, w = t >> 6;
  int wm = w >> 1, wn = w & 1;
  int lr = l & 15, lg = l >> 4;

  f32x4 zero = {0.f, 0.f, 0.f, 0.f};
  f32x4 acc[4][4];
#pragma unroll
  for (int i = 0; i < 4; i++)
#pragma unroll
    for (int j = 0; j < 4; j++) acc[i][j] = zero;

  for (int k0 = 0; k0 < K; k0 += 32) {
    __syncthreads();
#pragma unroll
    for (int i = 0; i < 2; i++) {
      int s = i * 256 + t;
      int r = s >> 2, c = s & 3;
      long ao = (long)sTok[r] * K + k0 + c * 8;
      gload16(Ah + ao, sAh + s * 8);
      gload16(Al + ao, sAl + s * 8);
      gload16(BT + (long)(n0 + r) * K + k0 + c * 8, sBT + s * 8);
    }
    __syncthreads();
    bf16x8 fah[4], fal[4], fbb[4];
#pragma unroll
    for (int f = 0; f < 4; f++) {
      int ra = wm * 64 + f * 16 + lr;
      fah[f] = *(const bf16x8*)(sAh + ra * 32 + lg * 8);
      fal[f] = *(const bf16x8*)(sAl + ra * 32 + lg * 8);
      int rb = wn * 64 + f * 16 + lr;
      fbb[f] = *(const bf16x8*)(sBT + rb * 32 + lg * 8);
    }
#pragma unroll
    for (int i = 0; i < 4; i++)
#pragma unroll
      for (int j = 0; j < 4; j++) {
        acc[i][j] = __builtin_amdgcn_mfma_f32_16x16x32_bf16(fah[i], fbb[j], acc[i][j], 0, 0, 0);
        acc[i][j] = __builtin_amdgcn_mfma_f32_16x16x32_bf16(fal[i], fbb[j], acc[i][j], 0, 0, 0);
      }
  }

  // C/D layout: col = lane&15, row = (lane>>4)*4 + reg
#pragma unroll
  for (int i = 0; i < 4; i++) {
#pragma unroll
    for (int j = 0; j < 4; j++) {
#pragma unroll
      for (int q = 0; q < 4; q++) {
        int widx = wm * 64 + i * 16 + lg * 4 + q;
        int col = n0 + wn * 64 + j * 16 + lr;
        bool valid = (m0 + widx) < cnt;
        int tok = sTok[widx];
        float gv = valid ? gelu_f(acc[i][j][q]) * wfull[(long)tok * 8 + eidx] : 0.f;
        u16 hh = f2b(gv);
        long idx = (long)(m0 + widx) * N + col;
        Ch[idx] = hh;
        Cl[idx] = f2b(gv - b2f(hh));
      }
    }
  }
}

// ---- SPARSE MoE W2: 128x64 tile, split-K=2 into two buffers, NO atomics.
// moeZ[tok(r)] += hid[r] @ W2T^T over its K-half; unique writer per (tok,col,z).
__global__ __launch_bounds__(256) void moe_w2_k(
    const u16* __restrict__ Ah, const u16* __restrict__ Al, const u16* __restrict__ BT,
    float* __restrict__ C0, float* __restrict__ C1,
    const int* __restrict__ elist, const int* __restrict__ ecnt, int eidx) {
  constexpr int N = Dm, K = FHid;
  int cnt = ecnt[eidx];
  int m0 = blockIdx.y * 128, n0 = blockIdx.x * 64;
  if (m0 >= cnt) return;
  float* C = blockIdx.z ? C1 : C0;
  int kbeg = blockIdx.z * (K / 2), kend = kbeg + K / 2;
  __shared__ __align__(16) u16 sAh[128 * 32];
  __shared__ __align__(16) u16 sAl[128 * 32];
  __shared__ __align__(16) u16 sBT[64 * 32];
  __shared__ int sTok[128];
  int t = threadIdx.x;
  if (t < 128) {
    int r = m0 + t;
    sTok[t] = (r < cnt) ? elist[eidx * Sq + r] : elist[eidx * Sq];
  }
  int l = t & 63, w = t >> 6;
  int wm = w >> 1, wn = w & 1;
  int lr = l & 15, lg = l >> 4;

  f32x4 zero = {0.f, 0.f, 0.f, 0.f};
  f32x4 acc[4][2];
#pragma unroll
  for (int i = 0; i < 4; i++)
#pragma unroll
    for (int j = 0; j < 2; j++) acc[i][j] = zero;

  for (int k0 = kbeg; k0 < kend; k0 += 32) {
    __syncthreads();
#pragma unroll
    for (int i = 0; i < 2; i++) {
      int s = i * 256 + t;
      int r = s >> 2, c = s & 3;
      long ao = (long)(m0 + r) * K + k0 + c * 8;  // hid is compacted: direct rows
      gload16(Ah + ao, sAh + s * 8);
      gload16(Al + ao, sAl + s * 8);
    }
    {
      int r = t >> 2, c = t & 3;  // 64 rows x 4 slots
      gload16(BT + (long)(n0 + r) * K + k0 + c * 8, sBT + t * 8);
    }
    __syncthreads();
    bf16x8 fah[4], fal[4], fbb[2];
#pragma unroll
    for (int f = 0; f < 4; f++) {
      int ra = wm * 64 + f * 16 + lr;
      fah[f] = *(const bf16x8*)(sAh + ra * 32 + lg * 8);
      fal[f] = *(const bf16x8*)(sAl + ra * 32 + lg * 8);
    }
#pragma unroll
    for (int j = 0; j < 2; j++) {
      int rb = wn * 32 + j * 16 + lr;
      fbb[j] = *(const bf16x8*)(sBT + rb * 32 + lg * 8);
    }
#pragma unroll
    for (int i = 0; i < 4; i++)
#pragma unroll
      for (int j = 0; j < 2; j++) {
        acc[i][j] = __builtin_amdgcn_mfma_f32_16x16x32_bf16(fah[i], fbb[j], acc[i][j], 0, 0, 0);
        acc[i][j] = __builtin_amdgcn_mfma_f32_16x16x32_bf16(fal[i], fbb[j], acc[i][j], 0, 0, 0);
      }
  }

#pragma unroll
  for (int i = 0; i < 4; i++) {
#pragma unroll
    for (int j = 0; j < 2; j++) {
#pragma unroll
      for (int q = 0; q < 4; q++) {
        int widx = wm * 64 + i * 16 + lg * 4 + q;
        int col = n0 + wn * 32 + j * 16 + lr;
        if ((m0 + widx) < cnt) {
          int tok = sTok[widx];
          C[(long)tok * N + col] += acc[i][j][q];
        }
      }
    }
  }
}

// ------------------------------- launcher -------------------------------
extern "C" void kernel_launch(void* const* d_in, const int* in_sizes, int n_in,
                              void* d_out, int out_size, void* d_ws, size_t ws_size,
                              hipStream_t stream) {
  (void)in_sizes; (void)n_in;
  const void* x = d_in[0];
  const void* Wq = d_in[1];
  const void* Wk = d_in[2];
  const void* Wv = d_in[3];
  const void* Wo = d_in[4];
  const void* gpre = d_in[5];
  const void* gpost = d_in[6];
  const void* gpm = d_in[7];
  const void* gpo = d_in[8];
  const void* Wr = d_in[9];
  const void* W1 = d_in[10];
  const void* W2 = d_in[11];

  // EXACT round-2/4 workspace layout (~89 MB, proven), with phase aliases.
  char* ws = (char*)d_ws;
  size_t off = 0;
  auto AL = [&](size_t b) { size_t o = off; off += (b + 255) & ~(size_t)255; return o; };
  const size_t oFlag = AL(16);
  const size_t oWf = AL((size_t)Sq * NE * 4);
  const size_t oHid = AL((size_t)Sq * FHid * 4);  // 32MB: MoE hid bf16 pair
  const size_t oH2 = AL((size_t)Sq * Dm * 4);     // h2f
  const size_t oX2 = AL((size_t)Sq * Dm * 4);     // x2
  const size_t oMoe = AL((size_t)Sq * Dm * 4);    // moe f32 accumulator (K-half 0)
  const size_t oAp = AL((size_t)Sq * Dm * 4);     // attnp -> (MoE) W2T bf16
  const size_t oAt = AL((size_t)Sq * Dm * 4);     // attnf -> (MoE) W1T bf16
  const size_t oVf = AL((size_t)Sq * HDim * 4);   // vf -> (MoE) ecnt + elist
  const size_t oKf = AL((size_t)Sq * HDim * 4);
  const size_t oQf = AL((size_t)Sq * Dm * 4);     // qf -> (MoE) h2 bf16 pair
  const size_t oH1 = AL((size_t)Sq * Dm * 4);     // h1f -> (MoE) moe2 (K-half 1)
  if (off > ws_size || out_size != Sq * Dm + Sq * NE) return;

  float* h1f = (float*)(ws + oH1);
  float* qf = (float*)(ws + oQf);
  float* kf = (float*)(ws + oKf);
  float* vf = (float*)(ws + oVf);
  float* attnf = (float*)(ws + oAt);
  float* attnp = (float*)(ws + oAp);
  float* x2 = (float*)(ws + oX2);
  float* h2f = (float*)(ws + oH2);
  float* moe = (float*)(ws + oMoe);
  float* wfull = (float*)(ws + oWf);
  int* dflag = (int*)(ws + oFlag);
  // MoE-phase aliases (source buffers dead by then):
  u16* hidh = (u16*)(ws + oHid);
  u16* hidl = hidh + (size_t)Sq * FHid;
  u16* bt1 = (u16*)(ws + oAt);   // W1T (attnf dead after Wo GEMM)
  u16* bt2 = (u16*)(ws + oAp);   // W2T (attnp dead after step-5 rmsnorm)
  u16* h2h = (u16*)(ws + oQf);   // h2 pair (qf dead after attention)
  u16* h2l = h2h + (size_t)Sq * Dm;
  float* moe2 = (float*)(ws + oH1);    // h1f dead after projections
  int* ecnt = (int*)(ws + oVf);        // 8 ints (vf dead after attention)
  int* elist = (int*)(ws + oVf + 256); // 8*2048 ints = 64KB (oVf = 512KB)
  float* out_x = (float*)d_out;
  float* out_probs = out_x + (size_t)Sq * Dm;

  // 0) dtype detect
  detect_k<<<1, 256, 0, stream>>>((const u16*)x, dflag);

  // 1) h1 = rmsnorm(x, gpre)                       [baseline-identical]
  rmsnorm2_k<1, 0><<<Sq, 64, 0, stream>>>(x, gpre, nullptr, h1f, dflag, nullptr);

  // 2) projections                                 [bit-exact: per-element chain unchanged]
  gemm_big_k<<<dim3(Dm / 64, Sq / 128), 256, 0, stream>>>(h1f, Wq, qf, Sq, Dm, Dm, dflag);
  gemm_nn_k<0><<<dim3(HDim / 64, Sq / 64), 256, 0, stream>>>(h1f, Wk, 0, kf, Sq, HDim, Dm, nullptr, 0, dflag);
  gemm_nn_k<0><<<dim3(HDim / 64, Sq / 64), 256, 0, stream>>>(h1f, Wv, 0, vf, Sq, HDim, Dm, nullptr, 0, dflag);

  // 3) attention                                   [bit-exact, R4-verbatim]
  attn_f32_k<<<dim3(Sq / 64, NH), 256, 0, stream>>>(qf, kf, vf, attnf);

  // 4) attnp = attn @ Wo                           [bit-exact]
  gemm_big_k<<<dim3(Dm / 64, Sq / 128), 256, 0, stream>>>(attnf, Wo, attnp, Sq, Dm, Dm, dflag);

  // 5) x2 = x + rmsnorm(attnp, gpost); h2 = rmsnorm(x2, gpm)   [baseline-identical]
  rmsnorm2_k<0, 2><<<Sq, 64, 0, stream>>>(attnp, gpost, x, x2, dflag, nullptr);
  rmsnorm2_k<0, 0><<<Sq, 64, 0, stream>>>(x2, gpm, nullptr, h2f, dflag, nullptr);

  // 6) router: lane per (token,expert)             [selection bit-identical]
  hipMemsetAsync(ws + oVf, 0, 32, stream);  // zero ecnt
  router2_k<<<Sq * NE / 256, 256, 0, stream>>>(h2f, Wr, out_probs, wfull, dflag, ecnt, elist);

  // 7) h2 hi/lo pair for MFMA MoE
  split_pair_k<<<(Sq * Dm / 4 + 255) / 256, 256, 0, stream>>>(h2f, h2h, h2l, Sq * Dm / 4);

  // 8) SPARSE MoE: per expert, compacted tokens; split-K2 W2 without atomics
  hipMemsetAsync(ws + oMoe, 0, (size_t)Sq * Dm * 4, stream);
  hipMemsetAsync(ws + oH1, 0, (size_t)Sq * Dm * 4, stream);
  for (int e = 0; e < NE; e++) {
    transpose2_k<<<dim3(128, 128, 2), 256, 0, stream>>>(
        W1, W2, (long)e * Dm * FHid, bt1, bt2, dflag);
    moe_w1_k<<<dim3(FHid / 128, Sq / 128), 256, 0, stream>>>(
        h2h, h2l, bt1, hidh, hidl, wfull, elist, ecnt, e);
    moe_w2_k<<<dim3(Dm / 64, Sq / 128, 2), 256, 0, stream>>>(
        hidh, hidl, bt2, moe, moe2, elist, ecnt, e);
  }

  // 9) out = x2 + rmsnorm(moe + moe2, gpo)         [post-router f32 reorder only]
  rmsnorm2_k<2, 1><<<Sq, 64, 0, stream>>>(moe, gpo, x2, out_x, dflag, moe2);
}

// Round 6
// 2233.858 us; speedup vs baseline: 1.1260x; 1.1260x over previous
//
#include <hip/hip_runtime.h>

typedef unsigned short u16;

#define DEVFN static __device__ __forceinline__

constexpr int Sq = 2048, Dm = 1024, NH = 16, HDim = 64, NE = 8, FHid = 4096;

typedef __attribute__((ext_vector_type(8))) short bf16x8;
typedef __attribute__((ext_vector_type(4))) float f32x4;

DEVFN float b2f(u16 u) { return __uint_as_float(((unsigned)u) << 16); }
// round-to-nearest-even f32 -> bf16
DEVFN u16 f2b(float f) {
  unsigned u = __float_as_uint(f);
  return (u16)((u + 0x7fffu + ((u >> 16) & 1u)) >> 16);
}
DEVFN float gelu_f(float x) {
  float y = 0.7978845608028654f * (x + 0.044715f * x * x * x);
  float t = 1.0f - 2.0f / (__expf(2.0f * y) + 1.0f);
  return 0.5f * x * (1.0f + t);
}

DEVFN void gload16(const u16* g, u16* l) {
  __builtin_amdgcn_global_load_lds((const __attribute__((address_space(1))) void*)g,
                                   (__attribute__((address_space(3))) void*)l, 16, 0, 0);
}

// ---------------- input dtype detector: flag=1 if inputs are f32 ----------------
__global__ __launch_bounds__(256) void detect_k(const u16* __restrict__ x, int* __restrict__ flag) {
  int t = threadIdx.x;
  float mx = 0.f;
  for (int i = t; i < 4096; i += 256) mx = fmaxf(mx, fabsf(b2f(x[i])));
#pragma unroll
  for (int m = 32; m; m >>= 1) mx = fmaxf(mx, __shfl_xor(mx, m, 64));
  __shared__ float red[4];
  if ((t & 63) == 0) red[t >> 6] = mx;
  __syncthreads();
  if (t == 0) {
    float m2 = fmaxf(fmaxf(red[0], red[1]), fmaxf(red[2], red[3]));
    flag[0] = (m2 > 1e6f) ? 1 : 0;
  }
}

// ---- rmsnorm: ONE WAVE per row (step 1 only).  INM1: input dtype per flag. ----
__global__ __launch_bounds__(64) void rmsnorm_in_k(const void* __restrict__ inp, const void* __restrict__ g,
                                                   float* __restrict__ out1, const int* __restrict__ dflag) {
  int isf = dflag[0];
  int row = blockIdx.x, t = threadIdx.x;
  long rb = (long)row * Dm;
  float v[16];
#pragma unroll
  for (int j = 0; j < 4; j++) {
    long o = rb + t * 4 + j * 256;
    if (isf) {
      float4 f = *((const float4*)((const float*)inp + o));
      v[4 * j] = f.x; v[4 * j + 1] = f.y; v[4 * j + 2] = f.z; v[4 * j + 3] = f.w;
    } else {
      ushort4 u = *((const ushort4*)((const u16*)inp + o));
      v[4 * j] = b2f(u.x); v[4 * j + 1] = b2f(u.y); v[4 * j + 2] = b2f(u.z); v[4 * j + 3] = b2f(u.w);
    }
  }
  float ss = 0.f;
#pragma unroll
  for (int j = 0; j < 16; j++) ss += v[j] * v[j];
#pragma unroll
  for (int m = 32; m; m >>= 1) ss += __shfl_xor(ss, m, 64);
  float sc = rsqrtf(ss * (1.0f / Dm) + 1e-5f);
#pragma unroll
  for (int j = 0; j < 4; j++) {
    long o = rb + t * 4 + j * 256;
    int go = t * 4 + j * 256;
    float gf[4];
    if (isf) {
      float4 gv = *((const float4*)((const float*)g + go));
      gf[0] = gv.x; gf[1] = gv.y; gf[2] = gv.z; gf[3] = gv.w;
    } else {
      ushort4 gu = *((const ushort4*)((const u16*)g + go));
      gf[0] = b2f(gu.x); gf[1] = b2f(gu.y); gf[2] = b2f(gu.z); gf[3] = b2f(gu.w);
    }
    float4 of;
    of.x = v[4 * j] * sc * gf[0];
    of.y = v[4 * j + 1] * sc * gf[1];
    of.z = v[4 * j + 2] * sc * gf[2];
    of.w = v[4 * j + 3] * sc * gf[3];
    *((float4*)(out1 + o)) = of;
  }
}

// ---- FUSED: x2 = x + rmsnorm(attnp, gpost); h2 = rmsnorm(x2, gpm).
// Second norm consumes the just-computed x2 registers (identical values) => bit-exact. ----
__global__ __launch_bounds__(64) void rmsnorm_fused_k(
    const float* __restrict__ attnp, const void* __restrict__ gpost, const void* __restrict__ xres,
    const void* __restrict__ gpm, float* __restrict__ x2, float* __restrict__ h2,
    const int* __restrict__ dflag) {
  int isf = dflag[0];
  int row = blockIdx.x, t = threadIdx.x;
  long rb = (long)row * Dm;
  float v[16];
#pragma unroll
  for (int j = 0; j < 4; j++) {
    long o = rb + t * 4 + j * 256;
    float4 f = *((const float4*)(attnp + o));
    v[4 * j] = f.x; v[4 * j + 1] = f.y; v[4 * j + 2] = f.z; v[4 * j + 3] = f.w;
  }
  float ss = 0.f;
#pragma unroll
  for (int j = 0; j < 16; j++) ss += v[j] * v[j];
#pragma unroll
  for (int m = 32; m; m >>= 1) ss += __shfl_xor(ss, m, 64);
  float sc = rsqrtf(ss * (1.0f / Dm) + 1e-5f);
  float xv[16];
#pragma unroll
  for (int j = 0; j < 4; j++) {
    long o = rb + t * 4 + j * 256;
    int go = t * 4 + j * 256;
    float gf[4];
    if (isf) {
      float4 gv = *((const float4*)((const float*)gpost + go));
      gf[0] = gv.x; gf[1] = gv.y; gf[2] = gv.z; gf[3] = gv.w;
    } else {
      ushort4 gu = *((const ushort4*)((const u16*)gpost + go));
      gf[0] = b2f(gu.x); gf[1] = b2f(gu.y); gf[2] = b2f(gu.z); gf[3] = b2f(gu.w);
    }
    float o4[4];
#pragma unroll
    for (int q = 0; q < 4; q++) o4[q] = v[4 * j + q] * sc * gf[q];
    if (isf) {
      float4 rf = *((const float4*)((const float*)xres + o));
      o4[0] += rf.x; o4[1] += rf.y; o4[2] += rf.z; o4[3] += rf.w;
    } else {
      ushort4 ru = *((const ushort4*)((const u16*)xres + o));
      o4[0] += b2f(ru.x); o4[1] += b2f(ru.y); o4[2] += b2f(ru.z); o4[3] += b2f(ru.w);
    }
    float4 of;
    of.x = o4[0]; of.y = o4[1]; of.z = o4[2]; of.w = o4[3];
    *((float4*)(x2 + o)) = of;
    xv[4 * j] = o4[0]; xv[4 * j + 1] = o4[1]; xv[4 * j + 2] = o4[2]; xv[4 * j + 3] = o4[3];
  }
  // second rmsnorm on x2 values (identical to re-reading x2)
  float ss2 = 0.f;
#pragma unroll
  for (int j = 0; j < 16; j++) ss2 += xv[j] * xv[j];
#pragma unroll
  for (int m = 32; m; m >>= 1) ss2 += __shfl_xor(ss2, m, 64);
  float sc2 = rsqrtf(ss2 * (1.0f / Dm) + 1e-5f);
#pragma unroll
  for (int j = 0; j < 4; j++) {
    long o = rb + t * 4 + j * 256;
    int go = t * 4 + j * 256;
    float gf[4];
    if (isf) {
      float4 gv = *((const float4*)((const float*)gpm + go));
      gf[0] = gv.x; gf[1] = gv.y; gf[2] = gv.z; gf[3] = gv.w;
    } else {
      ushort4 gu = *((const ushort4*)((const u16*)gpm + go));
      gf[0] = b2f(gu.x); gf[1] = b2f(gu.y); gf[2] = b2f(gu.z); gf[3] = b2f(gu.w);
    }
    float4 of;
    of.x = xv[4 * j] * sc2 * gf[0];
    of.y = xv[4 * j + 1] * sc2 * gf[1];
    of.z = xv[4 * j + 2] * sc2 * gf[2];
    of.w = xv[4 * j + 3] * sc2 * gf[3];
    *((float4*)(h2 + o)) = of;
  }
}

// ---- FINAL: out = x2 + rmsnorm((P0+P1)+(S0+S1), gpo) ----
__global__ __launch_bounds__(64) void rmsnorm_moe_k(
    const float* __restrict__ p0, const float* __restrict__ p1,
    const float* __restrict__ s0, const float* __restrict__ s1,
    const void* __restrict__ g, const float* __restrict__ x2,
    float* __restrict__ out1, const int* __restrict__ dflag) {
  int isf = dflag[0];
  int row = blockIdx.x, t = threadIdx.x;
  long rb = (long)row * Dm;
  float v[16];
#pragma unroll
  for (int j = 0; j < 4; j++) {
    long o = rb + t * 4 + j * 256;
    float4 a = *((const float4*)(p0 + o));
    float4 b = *((const float4*)(p1 + o));
    float4 c = *((const float4*)(s0 + o));
    float4 d = *((const float4*)(s1 + o));
    v[4 * j] = (a.x + b.x) + (c.x + d.x);
    v[4 * j + 1] = (a.y + b.y) + (c.y + d.y);
    v[4 * j + 2] = (a.z + b.z) + (c.z + d.z);
    v[4 * j + 3] = (a.w + b.w) + (c.w + d.w);
  }
  float ss = 0.f;
#pragma unroll
  for (int j = 0; j < 16; j++) ss += v[j] * v[j];
#pragma unroll
  for (int m = 32; m; m >>= 1) ss += __shfl_xor(ss, m, 64);
  float sc = rsqrtf(ss * (1.0f / Dm) + 1e-5f);
#pragma unroll
  for (int j = 0; j < 4; j++) {
    long o = rb + t * 4 + j * 256;
    int go = t * 4 + j * 256;
    float gf[4];
    if (isf) {
      float4 gv = *((const float4*)((const float*)g + go));
      gf[0] = gv.x; gf[1] = gv.y; gf[2] = gv.z; gf[3] = gv.w;
    } else {
      ushort4 gu = *((const ushort4*)((const u16*)g + go));
      gf[0] = b2f(gu.x); gf[1] = b2f(gu.y); gf[2] = b2f(gu.z); gf[3] = b2f(gu.w);
    }
    float4 rf = *((const float4*)(x2 + o));
    float4 of;
    of.x = v[4 * j] * sc * gf[0] + rf.x;
    of.y = v[4 * j + 1] * sc * gf[1] + rf.y;
    of.z = v[4 * j + 2] * sc * gf[2] + rf.z;
    of.w = v[4 * j + 3] * sc * gf[3] + rf.w;
    *((float4*)(out1 + o)) = of;
  }
}

// ---- FUSED Q/K/V projections: 128x64 f32 tile, 8x4 acc. bx<16: Wq; 16: Wk; 17: Wv.
// Per-output FMA chain = sequential k ascending => bit-exact vs baseline. ----
__global__ __launch_bounds__(256) void gemm_qkv_k(
    const float* __restrict__ A, const void* __restrict__ WqB, const void* __restrict__ WkB,
    const void* __restrict__ WvB, float* __restrict__ qf, float* __restrict__ kf,
    float* __restrict__ vf, const int* __restrict__ dflag) {
  int isf = dflag[0];
  int bx = blockIdx.x;
  const void* Braw;
  float* C;
  int N, n0;
  if (bx < 16) { Braw = WqB; C = qf; N = 1024; n0 = bx * 64; }
  else if (bx == 16) { Braw = WkB; C = kf; N = 64; n0 = 0; }
  else { Braw = WvB; C = vf; N = 64; n0 = 0; }
  const float* Bf = (const float*)Braw;
  const u16* Bh = (const u16*)Braw;
  int t = threadIdx.x;
  int m0 = blockIdx.y * 128;
  constexpr int K = Dm;

  __shared__ float As[128][21];
  __shared__ float Bs[16][68];

  int ty = t >> 4, tx = t & 15;
  float acc[8][4];
#pragma unroll
  for (int i = 0; i < 8; i++)
#pragma unroll
    for (int j = 0; j < 4; j++) acc[i][j] = 0.f;

  for (int k0 = 0; k0 < K; k0 += 16) {
    __syncthreads();
#pragma unroll
    for (int i = 0; i < 8; i++) {
      int idx = t + i * 256;
      int ar = idx >> 4, ac = idx & 15;
      As[ar][ac] = A[(long)(m0 + ar) * K + k0 + ac];
    }
#pragma unroll
    for (int i = 0; i < 4; i++) {
      int idx = t + i * 256;
      int br = idx >> 6, bc = idx & 63;
      long bi = (long)(k0 + br) * N + n0 + bc;
      Bs[br][bc] = isf ? Bf[bi] : b2f(Bh[bi]);
    }
    __syncthreads();
#pragma unroll
    for (int kk = 0; kk < 16; kk++) {
      float a[8], b[4];
#pragma unroll
      for (int i = 0; i < 8; i++) a[i] = As[ty * 8 + i][kk];
#pragma unroll
      for (int j = 0; j < 4; j++) b[j] = Bs[kk][tx * 4 + j];
#pragma unroll
      for (int i = 0; i < 8; i++)
#pragma unroll
        for (int j = 0; j < 4; j++) acc[i][j] += a[i] * b[j];
    }
  }
#pragma unroll
  for (int i = 0; i < 8; i++) {
    int row = m0 + ty * 8 + i;
#pragma unroll
    for (int j = 0; j < 4; j++) {
      int col = n0 + tx * 4 + j;
      C[(long)row * N + col] = acc[i][j];
    }
  }
}

// ---------------- f32 GEMM 128x64 tile (Wo), bit-exact chain ----
__global__ __launch_bounds__(256) void gemm_big_k(
    const float* __restrict__ A, const void* __restrict__ Braw,
    float* __restrict__ C, int M, int N, int K, const int* __restrict__ dflag) {
  int isf = dflag[0];
  const float* Bf = (const float*)Braw;
  const u16* Bh = (const u16*)Braw;
  int t = threadIdx.x;
  int m0 = blockIdx.y * 128, n0 = blockIdx.x * 64;

  __shared__ float As[128][21];
  __shared__ float Bs[16][68];

  int ty = t >> 4, tx = t & 15;
  float acc[8][4];
#pragma unroll
  for (int i = 0; i < 8; i++)
#pragma unroll
    for (int j = 0; j < 4; j++) acc[i][j] = 0.f;

  for (int k0 = 0; k0 < K; k0 += 16) {
    __syncthreads();
#pragma unroll
    for (int i = 0; i < 8; i++) {
      int idx = t + i * 256;
      int ar = idx >> 4, ac = idx & 15;
      As[ar][ac] = A[(long)(m0 + ar) * K + k0 + ac];
    }
#pragma unroll
    for (int i = 0; i < 4; i++) {
      int idx = t + i * 256;
      int br = idx >> 6, bc = idx & 63;
      long bi = (long)(k0 + br) * N + n0 + bc;
      Bs[br][bc] = isf ? Bf[bi] : b2f(Bh[bi]);
    }
    __syncthreads();
#pragma unroll
    for (int kk = 0; kk < 16; kk++) {
      float a[8], b[4];
#pragma unroll
      for (int i = 0; i < 8; i++) a[i] = As[ty * 8 + i][kk];
#pragma unroll
      for (int j = 0; j < 4; j++) b[j] = Bs[kk][tx * 4 + j];
#pragma unroll
      for (int i = 0; i < 8; i++)
#pragma unroll
        for (int j = 0; j < 4; j++) acc[i][j] += a[i] * b[j];
    }
  }
#pragma unroll
  for (int i = 0; i < 8; i++) {
    int row = m0 + ty * 8 + i;
#pragma unroll
    for (int j = 0; j < 4; j++) {
      int col = n0 + tx * 4 + j;
      C[(long)row * N + col] = acc[i][j];
    }
  }
}

// ---------------- plain-f32 attention: arithmetic chain VERBATIM baseline.
// float4 LDS reads in QK and PV inner loops (same ascending-d FMA order => bit-exact). ----
__global__ __launch_bounds__(256) void attn_f32_k(
    const float* __restrict__ Qf, const float* __restrict__ Kf, const float* __restrict__ Vf,
    float* __restrict__ Of) {
  int qb = blockIdx.x, h = blockIdx.y;
  int t = threadIdx.x;
  int qr = t >> 2;
  int sub = t & 3;
  __shared__ float Ks[64][68];
  __shared__ float Vs[64][68];
  int qrow = qb * 64 + qr;
  const float* qp = Qf + (long)qrow * Dm + h * HDim + sub * 16;
  float qfr[16];
#pragma unroll
  for (int j = 0; j < 16; j += 4) {
    float4 v = *(const float4*)(qp + j);
    qfr[j] = v.x; qfr[j + 1] = v.y; qfr[j + 2] = v.z; qfr[j + 3] = v.w;
  }
  float o[16];
#pragma unroll
  for (int j = 0; j < 16; j++) o[j] = 0.f;
  float m_i = -3e38f, l_i = 0.f;

  for (int kb = 0; kb < Sq / 64; kb++) {
    __syncthreads();
#pragma unroll
    for (int i = 0; i < 2; i++) {
      int idx = t + i * 256;
      int r = idx >> 3, c8 = (idx & 7) * 8;
      const float* kp = Kf + (long)(kb * 64 + r) * HDim + c8;
      float4 a = *(const float4*)(kp);
      float4 b = *(const float4*)(kp + 4);
      *(float4*)&Ks[r][c8] = a;
      *(float4*)&Ks[r][c8 + 4] = b;
      const float* vp = Vf + (long)(kb * 64 + r) * HDim + c8;
      float4 c = *(const float4*)(vp);
      float4 d = *(const float4*)(vp + 4);
      *(float4*)&Vs[r][c8] = c;
      *(float4*)&Vs[r][c8 + 4] = d;
    }
    __syncthreads();
    float s[64];
#pragma unroll
    for (int j = 0; j < 64; j++) {
      float acc = 0.f;
#pragma unroll
      for (int dq = 0; dq < 4; dq++) {
        float4 k4 = *(const float4*)&Ks[j][sub * 16 + dq * 4];
        acc += qfr[dq * 4 + 0] * k4.x;
        acc += qfr[dq * 4 + 1] * k4.y;
        acc += qfr[dq * 4 + 2] * k4.z;
        acc += qfr[dq * 4 + 3] * k4.w;
      }
      s[j] = acc;
    }
#pragma unroll
    for (int j = 0; j < 64; j++) {
      float v = s[j];
      v += __shfl_xor(v, 1, 64);
      v += __shfl_xor(v, 2, 64);
      s[j] = v * 0.125f;
    }
    float mx = s[0];
#pragma unroll
    for (int j = 1; j < 64; j++) mx = fmaxf(mx, s[j]);
    float mn = fmaxf(m_i, mx);
    float alpha = __expf(m_i - mn);
    m_i = mn;
    float ps = 0.f;
#pragma unroll
    for (int j = 0; j < 64; j++) {
      s[j] = __expf(s[j] - mn);
      ps += s[j];
    }
    l_i = l_i * alpha + ps;
#pragma unroll
    for (int d = 0; d < 16; d++) o[d] *= alpha;
#pragma unroll
    for (int j = 0; j < 64; j++) {
#pragma unroll
      for (int dq = 0; dq < 4; dq++) {
        float4 v4 = *(const float4*)&Vs[j][sub * 16 + dq * 4];
        o[dq * 4 + 0] += s[j] * v4.x;
        o[dq * 4 + 1] += s[j] * v4.y;
        o[dq * 4 + 2] += s[j] * v4.z;
        o[dq * 4 + 3] += s[j] * v4.w;
      }
    }
  }
  float inv = 1.0f / l_i;
#pragma unroll
  for (int d = 0; d < 16; d++)
    Of[(long)qrow * Dm + h * HDim + sub * 16 + d] = o[d] * inv;
}

// ---- router: ONE LANE PER (token, expert); selection arithmetic bit-identical (R5-proven).
// elist entries carry slot bit 15 (0=primary/i1, 1=secondary/i2).
__global__ __launch_bounds__(256) void router2_k(const float* __restrict__ h2, const void* __restrict__ Wr,
                                                 float* __restrict__ probs_out, float* __restrict__ wfull,
                                                 const int* __restrict__ dflag,
                                                 int* __restrict__ ecnt, int* __restrict__ elist) {
  int isf = dflag[0];
  int gid = blockIdx.x * 256 + threadIdx.x;
  int tok = gid >> 3, e = gid & 7;
  if (tok >= Sq) return;
  const float* hrow = h2 + (long)tok * Dm;
  float acc = 0.f;
  if (isf) {
    const float* wr = (const float*)Wr;
    for (int i = 0; i < Dm; i += 4) {
      float4 h4 = *(const float4*)(hrow + i);
      acc += h4.x * wr[(long)i * 8 + e];
      acc += h4.y * wr[(long)(i + 1) * 8 + e];
      acc += h4.z * wr[(long)(i + 2) * 8 + e];
      acc += h4.w * wr[(long)(i + 3) * 8 + e];
    }
  } else {
    const u16* wr = (const u16*)Wr;
    for (int i = 0; i < Dm; i += 4) {
      float4 h4 = *(const float4*)(hrow + i);
      acc += h4.x * b2f(wr[(long)i * 8 + e]);
      acc += h4.y * b2f(wr[(long)(i + 1) * 8 + e]);
      acc += h4.z * b2f(wr[(long)(i + 2) * 8 + e]);
      acc += h4.w * b2f(wr[(long)(i + 3) * 8 + e]);
    }
  }
  int lane = threadIdx.x & 63;
  int gbase = lane & ~7;
  float vals[8];
#pragma unroll
  for (int e2 = 0; e2 < 8; e2++) vals[e2] = __shfl(acc, gbase + e2, 64);
  int i1 = 0;
#pragma unroll
  for (int e2 = 1; e2 < 8; e2++)
    if (vals[e2] > vals[i1]) i1 = e2;
  int i2 = (i1 == 0) ? 1 : 0;
#pragma unroll
  for (int e2 = 0; e2 < 8; e2++)
    if (e2 != i1 && vals[e2] > vals[i2]) i2 = e2;
  float mx = vals[i1];
  float pr[8], s = 0.f;
#pragma unroll
  for (int e2 = 0; e2 < 8; e2++) { pr[e2] = expf(vals[e2] - mx); s += pr[e2]; }
  float inv = 1.0f / s;
  float pe = pr[e] * inv;
  probs_out[(long)tok * 8 + e] = pe;
  wfull[(long)tok * 8 + e] = (e == i1 || e == i2) ? pe : 0.f;
  if (e == 0) {
    int p1 = atomicAdd(&ecnt[i1], 1);
    elist[i1 * Sq + p1] = tok;            // primary (slot 0)
    int p2 = atomicAdd(&ecnt[i2], 1);
    elist[i2 * Sq + p2] = tok | 0x8000;   // secondary (slot 1)
  }
}

// ---- split f32 -> (hi, lo) bf16 pair (2^-16): MoE h2 (post-router) ----
__global__ __launch_bounds__(256) void split_pair_k(const float* __restrict__ in, u16* __restrict__ hi,
                                                    u16* __restrict__ lo, int n4) {
  int i = blockIdx.x * 256 + threadIdx.x;
  if (i >= n4) return;
  float4 v = ((const float4*)in)[i];
  ushort4 h, l;
  h.x = f2b(v.x); l.x = f2b(v.x - b2f(h.x));
  h.y = f2b(v.y); l.y = f2b(v.y - b2f(h.y));
  h.z = f2b(v.z); l.z = f2b(v.z - b2f(h.z));
  h.w = f2b(v.w); l.w = f2b(v.w - b2f(h.w));
  ((ushort4*)hi)[i] = h;
  ((ushort4*)lo)[i] = l;
}

// ---- expert/tile mapping helper: blockIdx.y -> (expert, local m0, prefix base, cnt) ----
DEVFN bool map_tile(const int* ecnt, int by, int& e, int& m0, int& base, int& cnt) {
  int cum = 0, cumc = 0;
  e = -1;
#pragma unroll
  for (int ee = 0; ee < 8; ee++) {
    int c = ecnt[ee];
    int tt = (c + 127) >> 7;
    if (e < 0 && by >= cum && by < cum + tt) {
      e = ee; m0 = (by - cum) << 7; base = cumc; cnt = c;
    }
    cum += tt; cumc += c;
  }
  return e >= 0;
}

// ---- ALL-EXPERT MoE W1: hid[base+r] = bf16(gelu((h2h+h2l)[tok(r)] @ W1[e]) * w).
// B staged with on-the-fly transpose from W1 [Dm][FHid] (no pre-transpose kernel).
__global__ __launch_bounds__(256) void moe_w1_all_k(
    const u16* __restrict__ Ah, const u16* __restrict__ Al, const void* __restrict__ W1raw,
    u16* __restrict__ hid, const float* __restrict__ wfull,
    const int* __restrict__ elist, const int* __restrict__ ecnt, const int* __restrict__ dflag) {
  constexpr int N = FHid, K = Dm;
  int isf = dflag[0];
  int e, m0, base, cnt;
  if (!map_tile(ecnt, blockIdx.y, e, m0, base, cnt)) return;
  int n0 = blockIdx.x * 128;
  const float* W1f = (const float*)W1raw + (long)e * K * N;
  const u16* W1h = (const u16*)W1raw + (long)e * K * N;

  __shared__ __align__(16) u16 sAh[128 * 32];
  __shared__ __align__(16) u16 sAl[128 * 32];
  __shared__ __align__(16) u16 sBT[128 * 32];
  __shared__ int sTok[128];
  int t = threadIdx.x;
  if (t < 128) {
    int r = m0 + t;
    sTok[t] = (r < cnt) ? elist[e * Sq + r] : elist[e * Sq];
  }
  int l = t & 63, w = t >> 6;
  int wm = w >> 1, wn = w & 1;
  int lr = l & 15, lg = l >> 4;

  f32x4 zero = {0.f, 0.f, 0.f, 0.f};
  f32x4 acc[4][4];
#pragma unroll
  for (int i = 0; i < 4; i++)
#pragma unroll
    for (int j = 0; j < 4; j++) acc[i][j] = zero;

  for (int k0 = 0; k0 < K; k0 += 32) {
    __syncthreads();
    // A: gather token rows via global_load_lds
#pragma unroll
    for (int i = 0; i < 2; i++) {
      int s = i * 256 + t;
      int r = s >> 2, c = s & 3;
      long ao = (long)(sTok[r] & 0x7fff) * K + k0 + c * 8;
      gload16(Ah + ao, sAh + s * 8);
      gload16(Al + ao, sAl + s * 8);
    }
    // B: on-the-fly transpose [k][n] -> sBT[n][k]; 8 strided loads + 1 b128 LDS write
#pragma unroll
    for (int i = 0; i < 2; i++) {
      int s = i * 256 + t;
      int nr = s >> 2, kc = (s & 3) * 8;
      u16 bv[8];
#pragma unroll
      for (int j = 0; j < 8; j++) {
        long bi = (long)(k0 + kc + j) * N + n0 + nr;
        bv[j] = isf ? f2b(W1f[bi]) : W1h[bi];
      }
      *(bf16x8*)(sBT + nr * 32 + kc) = *(bf16x8*)bv;
    }
    __syncthreads();
    bf16x8 fah[4], fal[4], fbb[4];
#pragma unroll
    for (int f = 0; f < 4; f++) {
      int ra = wm * 64 + f * 16 + lr;
      fah[f] = *(const bf16x8*)(sAh + ra * 32 + lg * 8);
      fal[f] = *(const bf16x8*)(sAl + ra * 32 + lg * 8);
      int rb = wn * 64 + f * 16 + lr;
      fbb[f] = *(const bf16x8*)(sBT + rb * 32 + lg * 8);
    }
#pragma unroll
    for (int i = 0; i < 4; i++)
#pragma unroll
      for (int j = 0; j < 4; j++) {
        acc[i][j] = __builtin_amdgcn_mfma_f32_16x16x32_bf16(fah[i], fbb[j], acc[i][j], 0, 0, 0);
        acc[i][j] = __builtin_amdgcn_mfma_f32_16x16x32_bf16(fal[i], fbb[j], acc[i][j], 0, 0, 0);
      }
  }

  // C/D layout: col = lane&15, row = (lane>>4)*4 + reg
#pragma unroll
  for (int i = 0; i < 4; i++) {
#pragma unroll
    for (int j = 0; j < 4; j++) {
#pragma unroll
      for (int q = 0; q < 4; q++) {
        int widx = wm * 64 + i * 16 + lg * 4 + q;
        if ((m0 + widx) < cnt) {
          int col = n0 + wn * 64 + j * 16 + lr;
          int tok = sTok[widx] & 0x7fff;
          float gv = gelu_f(acc[i][j][q]) * wfull[(long)tok * 8 + e];
          hid[(long)(base + m0 + widx) * N + col] = f2b(gv);
        }
      }
    }
  }
}

// ---- ALL-EXPERT MoE W2: C[tok] = hid[row] @ W2[e], slot-split x split-K2, plain stores.
__global__ __launch_bounds__(256) void moe_w2_all_k(
    const u16* __restrict__ hid, const void* __restrict__ W2raw,
    float* __restrict__ P0, float* __restrict__ P1, float* __restrict__ S0, float* __restrict__ S1,
    const int* __restrict__ elist, const int* __restrict__ ecnt, const int* __restrict__ dflag) {
  constexpr int N = Dm, K = FHid;
  int isf = dflag[0];
  int e, m0, base, cnt;
  if (!map_tile(ecnt, blockIdx.y, e, m0, base, cnt)) return;
  int n0 = blockIdx.x * 64;
  int z = blockIdx.z;
  int kbeg = z * (K / 2), kend = kbeg + K / 2;
  const float* W2f = (const float*)W2raw + (long)e * K * N;
  const u16* W2h = (const u16*)W2raw + (long)e * K * N;

  __shared__ __align__(16) u16 sA[128 * 32];
  __shared__ __align__(16) u16 sBT[64 * 32];
  __shared__ int sTok[128];
  __shared__ int sRow[128];
  int t = threadIdx.x;
  if (t < 128) {
    int r = m0 + t;
    sTok[t] = (r < cnt) ? elist[e * Sq + r] : elist[e * Sq];
    sRow[t] = base + ((r < cnt) ? r : (cnt - 1));
  }
  int l = t & 63, w = t >> 6;
  int wm = w >> 1, wn = w & 1;
  int lr = l & 15, lg = l >> 4;

  f32x4 zero = {0.f, 0.f, 0.f, 0.f};
  f32x4 acc[4][2];
#pragma unroll
  for (int i = 0; i < 4; i++)
#pragma unroll
    for (int j = 0; j < 2; j++) acc[i][j] = zero;

  for (int k0 = kbeg; k0 < kend; k0 += 32) {
    __syncthreads();
#pragma unroll
    for (int i = 0; i < 2; i++) {
      int s = i * 256 + t;
      int r = s >> 2, c = s & 3;
      long ao = (long)sRow[r] * K + k0 + c * 8;
      gload16(hid + ao, sA + s * 8);
    }
    {
      int nr = t >> 2, kc = (t & 3) * 8;  // 64 rows x 4 k-slots
      u16 bv[8];
#pragma unroll
      for (int j = 0; j < 8; j++) {
        long bi = (long)(k0 + kc + j) * N + n0 + nr;
        bv[j] = isf ? f2b(W2f[bi]) : W2h[bi];
      }
      *(bf16x8*)(sBT + nr * 32 + kc) = *(bf16x8*)bv;
    }
    __syncthreads();
    bf16x8 fa[4], fbb[2];
#pragma unroll
    for (int f = 0; f < 4; f++) {
      int ra = wm * 64 + f * 16 + lr;
      fa[f] = *(const bf16x8*)(sA + ra * 32 + lg * 8);
    }
#pragma unroll
    for (int j = 0; j < 2; j++) {
      int rb = wn * 32 + j * 16 + lr;
      fbb[j] = *(const bf16x8*)(sBT + rb * 32 + lg * 8);
    }
#pragma unroll
    for (int i = 0; i < 4; i++)
#pragma unroll
      for (int j = 0; j < 2; j++)
        acc[i][j] = __builtin_amdgcn_mfma_f32_16x16x32_bf16(fa[i], fbb[j], acc[i][j], 0, 0, 0);
  }

#pragma unroll
  for (int i = 0; i < 4; i++) {
#pragma unroll
    for (int j = 0; j < 2; j++) {
#pragma unroll
      for (int q = 0; q < 4; q++) {
        int widx = wm * 64 + i * 16 + lg * 4 + q;
        if ((m0 + widx) < cnt) {
          int v = sTok[widx];
          int tok = v & 0x7fff;
          float* C = (v & 0x8000) ? (z ? S1 : S0) : (z ? P1 : P0);
          int col = n0 + wn * 32 + j * 16 + lr;
          C[(long)tok * N + col] = acc[i][j][q];
        }
      }
    }
  }
}

// ------------------------------- launcher -------------------------------
extern "C" void kernel_launch(void* const* d_in, const int* in_sizes, int n_in,
                              void* d_out, int out_size, void* d_ws, size_t ws_size,
                              hipStream_t stream) {
  (void)in_sizes; (void)n_in;
  const void* x = d_in[0];
  const void* Wq = d_in[1];
  const void* Wk = d_in[2];
  const void* Wv = d_in[3];
  const void* Wo = d_in[4];
  const void* gpre = d_in[5];
  const void* gpost = d_in[6];
  const void* gpm = d_in[7];
  const void* gpo = d_in[8];
  const void* Wr = d_in[9];
  const void* W1 = d_in[10];
  const void* W2 = d_in[11];

  // EXACT proven workspace layout (~89 MB) with phase aliases.
  char* ws = (char*)d_ws;
  size_t off = 0;
  auto AL = [&](size_t b) { size_t o = off; off += (b + 255) & ~(size_t)255; return o; };
  const size_t oFlag = AL(16);
  const size_t oWf = AL((size_t)Sq * NE * 4);
  const size_t oHid = AL((size_t)Sq * FHid * 4);  // 32MB: hid bf16, 4096 compacted rows
  const size_t oH2 = AL((size_t)Sq * Dm * 4);     // h2f -> (MoE) moeS0
  const size_t oX2 = AL((size_t)Sq * Dm * 4);     // x2
  const size_t oMoe = AL((size_t)Sq * Dm * 4);    // moeP0
  const size_t oAp = AL((size_t)Sq * Dm * 4);     // attnp (dead after rms_fused)
  const size_t oAt = AL((size_t)Sq * Dm * 4);     // attnf -> (MoE) moeS1
  const size_t oVf = AL((size_t)Sq * HDim * 4);   // vf -> ecnt + elist
  const size_t oKf = AL((size_t)Sq * HDim * 4);
  const size_t oQf = AL((size_t)Sq * Dm * 4);     // qf -> h2 bf16 pair
  const size_t oH1 = AL((size_t)Sq * Dm * 4);     // h1f -> moeP1
  if (off > ws_size || out_size != Sq * Dm + Sq * NE) return;

  float* h1f = (float*)(ws + oH1);
  float* qf = (float*)(ws + oQf);
  float* kf = (float*)(ws + oKf);
  float* vf = (float*)(ws + oVf);
  float* attnf = (float*)(ws + oAt);
  float* attnp = (float*)(ws + oAp);
  float* x2 = (float*)(ws + oX2);
  float* h2f = (float*)(ws + oH2);
  float* wfull = (float*)(ws + oWf);
  int* dflag = (int*)(ws + oFlag);
  // MoE-phase aliases:
  u16* hid = (u16*)(ws + oHid);
  u16* h2h = (u16*)(ws + oQf);
  u16* h2l = h2h + (size_t)Sq * Dm;
  float* moeP0 = (float*)(ws + oMoe);
  float* moeP1 = (float*)(ws + oH1);
  float* moeS0 = (float*)(ws + oH2);
  float* moeS1 = (float*)(ws + oAt);
  int* ecnt = (int*)(ws + oVf);
  int* elist = (int*)(ws + oVf + 256);
  float* out_x = (float*)d_out;
  float* out_probs = out_x + (size_t)Sq * Dm;

  // 0) dtype detect
  detect_k<<<1, 256, 0, stream>>>((const u16*)x, dflag);

  // 1) h1 = rmsnorm(x, gpre)                       [baseline-identical]
  rmsnorm_in_k<<<Sq, 64, 0, stream>>>(x, gpre, h1f, dflag);

  // 2) Q/K/V projections in ONE launch             [bit-exact sequential-k chain]
  gemm_qkv_k<<<dim3(18, Sq / 128), 256, 0, stream>>>(h1f, Wq, Wk, Wv, qf, kf, vf, dflag);

  // 3) attention                                   [bit-exact chain; float4 LDS reads]
  attn_f32_k<<<dim3(Sq / 64, NH), 256, 0, stream>>>(qf, kf, vf, attnf);

  // 4) attnp = attn @ Wo                           [bit-exact]
  gemm_big_k<<<dim3(Dm / 64, Sq / 128), 256, 0, stream>>>(attnf, Wo, attnp, Sq, Dm, Dm, dflag);

  // 5) x2 + h2 in one fused launch                 [bit-exact]
  rmsnorm_fused_k<<<Sq, 64, 0, stream>>>(attnp, gpost, x, gpm, x2, h2f, dflag);

  // 6) router                                      [selection bit-identical]
  hipMemsetAsync(ws + oVf, 0, 32, stream);
  router2_k<<<Sq * NE / 256, 256, 0, stream>>>(h2f, Wr, out_probs, wfull, dflag, ecnt, elist);

  // 7) h2 hi/lo pair for MFMA MoE
  split_pair_k<<<(Sq * Dm / 4 + 255) / 256, 256, 0, stream>>>(h2f, h2h, h2l, Sq * Dm / 4);

  // 8) ALL-EXPERT sparse MoE in 2 launches (max 39 row-tiles across experts)
  moe_w1_all_k<<<dim3(FHid / 128, 39), 256, 0, stream>>>(
      h2h, h2l, W1, hid, wfull, elist, ecnt, dflag);
  moe_w2_all_k<<<dim3(Dm / 64, 39, 2), 256, 0, stream>>>(
      hid, W2, moeP0, moeP1, moeS0, moeS1, elist, ecnt, dflag);

  // 9) out = x2 + rmsnorm((P0+P1)+(S0+S1), gpo)    [post-router reorder only]
  rmsnorm_moe_k<<<Sq, 64, 0, stream>>>(moeP0, moeP1, moeS0, moeS1, gpo, x2, out_x, dflag);
}